// Round 8
// baseline (759.308 us; speedup 1.0000x reference)
//
#include <hip/hip_runtime.h>

#define DD    256    // feature dim
#define CC    100    // num classes
#define TPB   1024   // threads per block (16 waves)
#define CHUNK 1024   // rows per chunk (== TPB)
#define NB    128    // blocks (grid-stride over chunks)

typedef float f4 __attribute__((ext_vector_type(4)));

// Workspace layout (bytes):
//   [0, 102400)        : g_sums   (CC*DD f32, positional/transposed layout)
//   [102400, 102800)   : g_counts (CC int)
//   [102800, 102808)   : g_sumsq  (1 double)
#define WS_SUMS_OFF   0
#define WS_COUNTS_OFF (CC * DD * 4)
#define WS_SUMSQ_OFF  (WS_COUNTS_OFF + CC * 4)
#define WS_HDR        (WS_SUMSQ_OFF + 8)

// ---------------- fused pass: argmax + class-sum accumulate -----------------
// Rows with row < nt_rows are feature-loaded NON-TEMPORALLY (bypass/deprioritize
// cache allocation) so the remaining set {labels, features[nt_rows:]} (~242 MB)
// stays L3-resident across graph replays instead of LRU-thrashing all 356 MB.
__global__ __launch_bounds__(TPB) void affinity_pass1(
        const float* __restrict__ feats,
        const float* __restrict__ labels,
        float* __restrict__ g_sums,
        int*   __restrict__ g_counts,
        double* __restrict__ g_sumsq,
        int N, int nt_rows)
{
    __shared__ float  s_sums[CC * DD];   // 100 KB -> 1 block/CU
    __shared__ int    s_cls[CHUNK];
    __shared__ int    s_cnt[CC];
    __shared__ double s_red[TPB / 64];

    const int tid = threadIdx.x;
    for (int i = tid; i < CC * DD; i += TPB) s_sums[i] = 0.f;
    if (tid < CC) s_cnt[tid] = 0;
    // first loop-top __syncthreads makes these inits visible

    const int lane  = tid & 63;
    const int wid   = tid >> 6;
    const int wbase = wid * 64;          // this wave's 64 rows within a chunk
    float sumsq = 0.f;

    const int nchunks = (N + CHUNK - 1) / CHUNK;
    for (int ch = blockIdx.x; ch < nchunks; ch += NB) {
        const int base = ch * CHUNK;
        __syncthreads();   // prev phase-B done with s_cls; inits visible

        // ---------- phase A: one thread per row, register argmax ----------
        {
            const int row = base + tid;
            int cls = -1;
            if (row < N) {
                const f4* l4 = (const f4*)(labels + (size_t)row * CC);
                float best = -3.4e38f;
                int   bi   = 0;
                f4 q[8];
                #pragma unroll
                for (int b = 0; b < 3; ++b) {           // 3 batches of 8 loads
                    #pragma unroll
                    for (int j = 0; j < 8; ++j) q[j] = l4[b * 8 + j];
                    #pragma unroll
                    for (int j = 0; j < 8; ++j) {       // strict > = first-max
                        const int e = (b * 8 + j) * 4;
                        if (q[j][0] > best) { best = q[j][0]; bi = e; }
                        if (q[j][1] > best) { best = q[j][1]; bi = e + 1; }
                        if (q[j][2] > best) { best = q[j][2]; bi = e + 2; }
                        if (q[j][3] > best) { best = q[j][3]; bi = e + 3; }
                    }
                }
                {                                        // tail: elements 96..99
                    const f4 qz = l4[24];
                    if (qz[0] > best) { best = qz[0]; bi = 96; }
                    if (qz[1] > best) { best = qz[1]; bi = 97; }
                    if (qz[2] > best) { best = qz[2]; bi = 98; }
                    if (qz[3] > best) { best = qz[3]; bi = 99; }
                }
                cls = bi;
                atomicAdd(&s_cnt[bi], 1);               // native int LDS atomic
            }
            s_cls[tid] = cls;
        }
        __syncthreads();

        // ---------- phase B: wave loads full rows (64 lanes x f4 = 1 KB) ---
        // LDS layout transposed: element (4*lane+k) at s_sums[c*DD + k*64+lane]
        const int c64 = s_cls[wbase + lane];            // class of row wbase+lane

        #pragma unroll
        for (int h = 0; h < 4; ++h) {                   // 4 batches x 16 rows
            const int r0 = base + wbase + h * 16;

            f4 f[16];
            #pragma unroll
            for (int i = 0; i < 16; ++i) {              // 16 independent rows
                const int r  = r0 + i;                  // wave-uniform
                const int rr = (r < N) ? r : 0;
                const f4* p = (const f4*)(feats + (size_t)rr * DD) + lane;
                f[i] = (r < nt_rows) ? __builtin_nontemporal_load(p) : *p;
            }

            #pragma unroll
            for (int i = 0; i < 16; ++i) {
                const int c = __shfl(c64, h * 16 + i);  // readlane (const idx)
                if (c < 0) continue;                    // OOB row: uniform skip
                sumsq += f[i][0] * f[i][0] + f[i][1] * f[i][1]
                       + f[i][2] * f[i][2] + f[i][3] * f[i][3];
                float* dst = &s_sums[c * DD + lane];    // bank lane%32: free 2-way
                unsafeAtomicAdd(dst +   0, f[i][0]);    // ds_add_f32, no return
                unsafeAtomicAdd(dst +  64, f[i][1]);
                unsafeAtomicAdd(dst + 128, f[i][2]);
                unsafeAtomicAdd(dst + 192, f[i][3]);
            }
        }
    }

    // ---- sumsq: wave reduce -> block reduce -> one f64 atomic per block ----
    double ds = (double)sumsq;
    #pragma unroll
    for (int off = 1; off < 64; off <<= 1) ds += __shfl_xor(ds, off);
    if (lane == 0) s_red[wid] = ds;
    __syncthreads();   // also drains all ds_add_f32
    if (tid == 0) {
        double t = 0.0;
        #pragma unroll
        for (int i = 0; i < TPB / 64; ++i) t += s_red[i];
        atomicAdd(g_sumsq, t);
    }

    // ---- flush: fire-and-forget global f32 atomics (no partials pass) ----
    for (int i = tid; i < CC * DD; i += TPB) {
        const float s = s_sums[i];
        if (s != 0.f) unsafeAtomicAdd(&g_sums[i], s);   // global_atomic_add_f32
    }
    if (tid < CC) {
        const int c = s_cnt[tid];
        if (c) atomicAdd(&g_counts[tid], c);
    }
}

// ---------------- finalize ----------------------------------------------------
// Layout-transparent: each thread owns one POSITION (a permuted dim). All loss
// terms are sums over (class, dim); colmean is per-dim — both invariant under
// a per-dim permutation, so the transposed g_sums layout is fine.
__global__ __launch_bounds__(DD) void affinity_finalize(
        const float* __restrict__ g_sums,
        const int*   __restrict__ g_counts,
        const double* __restrict__ g_sumsq,
        float* __restrict__ out)
{
    const int d = threadIdx.x;

    double colsum = 0.0, s2 = 0.0, dot = 0.0, cc = 0.0;
    for (int c = 0; c < CC; ++c) {
        const int    cnt = g_counts[c];
        const float  s   = g_sums[c * DD + d];
        const double center = (cnt > 0 ? (double)s / (double)cnt : 0.0) + 1e-6;
        colsum += center;
        s2     += center * center;
        dot    += center * (double)s;
        cc     += (double)cnt * center * center;
    }
    double interp = s2 - colsum * colsum / (double)CC;

    __shared__ double red0[DD], red1[DD], red2[DD];
    red0[d] = dot; red1[d] = cc; red2[d] = interp;
    __syncthreads();
    for (int off = DD / 2; off > 0; off >>= 1) {
        if (d < off) {
            red0[d] += red0[d + off];
            red1[d] += red1[d + off];
            red2[d] += red2[d + off];
        }
        __syncthreads();
    }
    if (d == 0) {
        const double intra = *g_sumsq - 2.0 * red0[0] + red1[0];
        const double inter = red2[0] / (double)CC;
        out[0] = (float)(intra / (inter + 1e-6));
    }
}

extern "C" void kernel_launch(void* const* d_in, const int* in_sizes, int n_in,
                              void* d_out, int out_size, void* d_ws, size_t ws_size,
                              hipStream_t stream)
{
    const float* feats  = (const float*)d_in[0];
    const float* labels = (const float*)d_in[1];
    const int N = in_sizes[0] / DD;

    float*  g_sums   = (float*)((char*)d_ws + WS_SUMS_OFF);
    int*    g_counts = (int*)((char*)d_ws + WS_COUNTS_OFF);
    double* g_sumsq  = (double*)((char*)d_ws + WS_SUMSQ_OFF);

    // Non-temporal prefix: keep {labels(100MB) + feature tail(~142MB) + flush}
    // within the 256MB L3 -> the NT prefix is the only HBM re-fetch per replay.
    int nt_rows = N - 145408;
    if (nt_rows < 0) nt_rows = 0;
    nt_rows &= ~(CHUNK - 1);

    hipMemsetAsync(d_ws, 0, WS_HDR, stream);     // zero sums/counts/sumsq

    affinity_pass1<<<NB, TPB, 0, stream>>>(feats, labels, g_sums, g_counts,
                                           g_sumsq, N, nt_rows);
    affinity_finalize<<<1, DD, 0, stream>>>(g_sums, g_counts, g_sumsq,
                                            (float*)d_out);
}

// Round 9
// 171.059 us; speedup vs baseline: 4.4389x; 4.4389x over previous
//
#include <hip/hip_runtime.h>

#define DD   256    // feature dim
#define CC   100    // num classes
#define ABT  256    // argmax threads per block
#define SBT  1024   // scatter threads per block

typedef float f4 __attribute__((ext_vector_type(4)));

// Workspace layout (bytes):
//   [0, 102400)        : g_sums   (CC*DD f32, natural layout)
//   [102400, 102800)   : g_counts (CC int)
//   [102800, 103200)   : g_cursor (CC int)
//   [103200, 103208)   : g_sumsq  (1 double)
//   [103424, +4N)      : cls      (N int)
//   [+4N, +8N)         : order    (N int)
//   [+8N, +12N)        : scls     (N int)
#define WS_SUMS_OFF   0
#define WS_COUNTS_OFF (CC * DD * 4)
#define WS_CURSOR_OFF (WS_COUNTS_OFF + CC * 4)
#define WS_SUMSQ_OFF  (WS_CURSOR_OFF + CC * 4)
#define WS_HDR        (WS_SUMSQ_OFF + 8)
#define WS_CLS_OFF    103424

// ---------------- kernel A: per-row argmax + histogram ----------------------
__global__ __launch_bounds__(ABT) void k_argmax(
        const float* __restrict__ labels,
        int*   __restrict__ cls,
        int*   __restrict__ g_counts,
        int N)
{
    __shared__ int s_cnt[CC];
    const int tid = threadIdx.x;
    if (tid < CC) s_cnt[tid] = 0;
    __syncthreads();

    const int row = blockIdx.x * ABT + tid;
    if (row < N) {
        const f4* l4 = (const f4*)(labels + (size_t)row * CC);
        float best = -3.4e38f;
        int   bi   = 0;
        f4 q[8];
        #pragma unroll
        for (int b = 0; b < 3; ++b) {               // 3 batches of 8 loads
            #pragma unroll
            for (int j = 0; j < 8; ++j) q[j] = l4[b * 8 + j];
            #pragma unroll
            for (int j = 0; j < 8; ++j) {           // strict > = first-max
                const int e = (b * 8 + j) * 4;
                if (q[j][0] > best) { best = q[j][0]; bi = e; }
                if (q[j][1] > best) { best = q[j][1]; bi = e + 1; }
                if (q[j][2] > best) { best = q[j][2]; bi = e + 2; }
                if (q[j][3] > best) { best = q[j][3]; bi = e + 3; }
            }
        }
        {                                            // tail: elements 96..99
            const f4 qz = l4[24];
            if (qz[0] > best) { best = qz[0]; bi = 96; }
            if (qz[1] > best) { best = qz[1]; bi = 97; }
            if (qz[2] > best) { best = qz[2]; bi = 98; }
            if (qz[3] > best) { best = qz[3]; bi = 99; }
        }
        cls[row] = bi;
        atomicAdd(&s_cnt[bi], 1);                    // native int LDS atomic
    }
    __syncthreads();
    if (tid < CC) {
        const int c = s_cnt[tid];
        if (c) atomicAdd(&g_counts[tid], c);
    }
}

// ---------------- kernel S0: exclusive scan of counts -> cursors ------------
__global__ void k_scan(const int* __restrict__ g_counts,
                       int* __restrict__ g_cursor)
{
    if (threadIdx.x == 0) {
        int s = 0;
        for (int c = 0; c < CC; ++c) { g_cursor[c] = s; s += g_counts[c]; }
    }
}

// ---------------- kernel S1: scatter rows grouped by class ------------------
__global__ __launch_bounds__(SBT) void k_scatter(
        const int* __restrict__ cls,
        int* __restrict__ g_cursor,
        int* __restrict__ order,
        int* __restrict__ scls,
        int N)
{
    __shared__ int l_hist[CC];
    __shared__ int l_base[CC];
    const int tid = threadIdx.x;
    if (tid < CC) l_hist[tid] = 0;
    __syncthreads();

    const int row = blockIdx.x * SBT + tid;
    const int c = (row < N) ? cls[row] : -1;
    int lr = 0;
    if (c >= 0) lr = atomicAdd(&l_hist[c], 1);       // local rank (returns old)
    __syncthreads();
    if (tid < CC && l_hist[tid] > 0)
        l_base[tid] = atomicAdd(&g_cursor[tid], l_hist[tid]);
    __syncthreads();
    if (c >= 0) {
        const int pos = l_base[c] + lr;
        order[pos] = row;
        scls[pos]  = c;
    }
}

// ---------------- kernel B: sorted streaming class-sum accumulate -----------
// Wave streams 64 consecutive positions of order[]; one wave-instruction loads
// one FULL feature row (64 lanes x f4 = 1 KB). Accumulator lives in registers
// (runs of ~2600 same-class rows); flush = 4 global atomics per class change.
// NO LDS tile -> 32 waves/CU occupancy -> deep memory-level parallelism.
__global__ __launch_bounds__(256) void k_accum_sorted(
        const float* __restrict__ feats,
        const int*   __restrict__ order,
        const int*   __restrict__ scls,
        float* __restrict__ g_sums,
        double* __restrict__ g_sumsq,
        int N)
{
    const int lane = threadIdx.x & 63;
    const int wid  = threadIdx.x >> 6;
    const int chunk = (blockIdx.x * 4 + wid) * 64;   // this wave's 64 positions

    const int idx = chunk + lane;
    const int ord64 = (idx < N) ? order[idx] : 0;    // coalesced
    const int sc64  = (idx < N) ? scls[idx]  : -1;   // -1 = skip sentinel

    const f4* feats4 = (const f4*)feats;

    f4   acc = {0.f, 0.f, 0.f, 0.f};
    int  cur = -1;
    float ssq = 0.f;

    #pragma unroll
    for (int b = 0; b < 8; ++b) {                    // 8 batches x 8 rows
        f4  f[8];
        int cr[8];
        #pragma unroll
        for (int r = 0; r < 8; ++r) {                // 8 independent row loads
            const int rw = __shfl(ord64, b * 8 + r); // readlane (const index)
            cr[r] = __shfl(sc64, b * 8 + r);
            f[r] = feats4[(size_t)rw * (DD / 4) + lane];  // contiguous 1 KB/wave
        }
        #pragma unroll
        for (int r = 0; r < 8; ++r) {
            if (cr[r] != cur) {                      // wave-uniform, rare
                if (cur >= 0) {
                    float* dst = g_sums + (size_t)cur * DD + lane * 4;
                    unsafeAtomicAdd(dst + 0, acc[0]);
                    unsafeAtomicAdd(dst + 1, acc[1]);
                    unsafeAtomicAdd(dst + 2, acc[2]);
                    unsafeAtomicAdd(dst + 3, acc[3]);
                    acc = (f4){0.f, 0.f, 0.f, 0.f};
                }
                cur = cr[r];
            }
            if (cur >= 0) {
                acc += f[r];
                ssq += f[r][0] * f[r][0] + f[r][1] * f[r][1]
                     + f[r][2] * f[r][2] + f[r][3] * f[r][3];
            }
        }
    }
    if (cur >= 0) {                                  // final flush
        float* dst = g_sums + (size_t)cur * DD + lane * 4;
        unsafeAtomicAdd(dst + 0, acc[0]);
        unsafeAtomicAdd(dst + 1, acc[1]);
        unsafeAtomicAdd(dst + 2, acc[2]);
        unsafeAtomicAdd(dst + 3, acc[3]);
    }

    // sumsq: wave reduce -> one f64 atomic per wave (~4096 total)
    #pragma unroll
    for (int off = 1; off < 64; off <<= 1) ssq += __shfl_xor(ssq, off);
    if (lane == 0) atomicAdd(g_sumsq, (double)ssq);
}

// ---------------- finalize ---------------------------------------------------
__global__ __launch_bounds__(DD) void affinity_finalize(
        const float* __restrict__ g_sums,
        const int*   __restrict__ g_counts,
        const double* __restrict__ g_sumsq,
        float* __restrict__ out)
{
    const int d = threadIdx.x;

    double colsum = 0.0, s2 = 0.0, dot = 0.0, cc = 0.0;
    for (int c = 0; c < CC; ++c) {
        const int    cnt = g_counts[c];
        const float  s   = g_sums[c * DD + d];
        const double center = (cnt > 0 ? (double)s / (double)cnt : 0.0) + 1e-6;
        colsum += center;
        s2     += center * center;
        dot    += center * (double)s;
        cc     += (double)cnt * center * center;
    }
    double interp = s2 - colsum * colsum / (double)CC;

    __shared__ double red0[DD], red1[DD], red2[DD];
    red0[d] = dot; red1[d] = cc; red2[d] = interp;
    __syncthreads();
    for (int off = DD / 2; off > 0; off >>= 1) {
        if (d < off) {
            red0[d] += red0[d + off];
            red1[d] += red1[d + off];
            red2[d] += red2[d + off];
        }
        __syncthreads();
    }
    if (d == 0) {
        const double intra = *g_sumsq - 2.0 * red0[0] + red1[0];
        const double inter = red2[0] / (double)CC;
        out[0] = (float)(intra / (inter + 1e-6));
    }
}

extern "C" void kernel_launch(void* const* d_in, const int* in_sizes, int n_in,
                              void* d_out, int out_size, void* d_ws, size_t ws_size,
                              hipStream_t stream)
{
    const float* feats  = (const float*)d_in[0];
    const float* labels = (const float*)d_in[1];
    const int N = in_sizes[0] / DD;

    float*  g_sums   = (float*)((char*)d_ws + WS_SUMS_OFF);
    int*    g_counts = (int*)((char*)d_ws + WS_COUNTS_OFF);
    int*    g_cursor = (int*)((char*)d_ws + WS_CURSOR_OFF);
    double* g_sumsq  = (double*)((char*)d_ws + WS_SUMSQ_OFF);
    int*    cls      = (int*)((char*)d_ws + WS_CLS_OFF);
    int*    order    = cls + N;
    int*    scls     = order + N;

    hipMemsetAsync(d_ws, 0, WS_HDR, stream);     // zero sums/counts/cursor/sumsq

    const int nbA = (N + ABT - 1) / ABT;
    k_argmax<<<nbA, ABT, 0, stream>>>(labels, cls, g_counts, N);

    k_scan<<<1, 64, 0, stream>>>(g_counts, g_cursor);

    const int nbS = (N + SBT - 1) / SBT;
    k_scatter<<<nbS, SBT, 0, stream>>>(cls, g_cursor, order, scls, N);

    const int nbB = (N + 255) / 256;             // 4 waves x 64 rows per block
    k_accum_sorted<<<nbB, 256, 0, stream>>>(feats, order, scls, g_sums,
                                            g_sumsq, N);

    affinity_finalize<<<1, DD, 0, stream>>>(g_sums, g_counts, g_sumsq,
                                            (float*)d_out);
}

// Round 10
// 158.503 us; speedup vs baseline: 4.7905x; 1.0792x over previous
//
#include <hip/hip_runtime.h>

#define DD   256    // feature dim
#define CC   100    // num classes
#define SBT  1024   // scatter threads per block

typedef float f4 __attribute__((ext_vector_type(4)));

// Workspace layout (bytes):
//   [0, 102400)        : g_sums   (CC*DD f32, natural layout)
//   [102400, 102800)   : g_counts (CC int)
//   [102800, 103200)   : g_cursor (CC int)
//   [103200, 103208)   : g_sumsq  (1 double)
//   [103424, +4N)      : cls      (N int)
//   [+4N, +8N)         : order    (N int)
//   [+8N, +12N)        : scls     (N int)
#define WS_SUMS_OFF   0
#define WS_COUNTS_OFF (CC * DD * 4)
#define WS_CURSOR_OFF (WS_COUNTS_OFF + CC * 4)
#define WS_SUMSQ_OFF  (WS_CURSOR_OFF + CC * 4)
#define WS_HDR        (WS_SUMSQ_OFF + 8)
#define WS_CLS_OFF    103424

// ---------------- kernel A: argmax via DMA-staged LDS tiles -----------------
// Each wave owns a private 2x25.6KB LDS slice. Per 64-row tile: 25 coalesced
// global_load_lds (width 16) DMA the tile linearly; counted vmcnt(25) ping-pong
// keeps 25-50KB in flight per wave; each lane then argmaxes its own row from
// LDS. 3 waves/block, 1 block/CU: ~150KB/CU in flight -> HBM-bound streaming.
__global__ __launch_bounds__(192) void k_argmax(
        const float* __restrict__ labels,
        int*   __restrict__ cls,
        int*   __restrict__ g_counts,
        int N)
{
    __shared__ f4  stage[3][2][1600];    // 3 waves x 2 bufs x 25600 B = 150 KB
    __shared__ int s_cnt[CC];

    const int tid  = threadIdx.x;
    const int lane = tid & 63;
    const int wid  = tid >> 6;
    if (tid < CC) s_cnt[tid] = 0;
    __syncthreads();

    const int ntiles = N >> 6;
    const int S      = gridDim.x * 3;    // total waves

#define DMA(b_, t_) do {                                                      \
    const float* gbase = labels + (size_t)(t_) * 6400 + lane * 4;             \
    f4* lbase = &stage[wid][b_][0];                                           \
    _Pragma("unroll")                                                         \
    for (int i_ = 0; i_ < 25; ++i_)                                           \
        __builtin_amdgcn_global_load_lds(                                     \
            (const __attribute__((address_space(1))) unsigned int*)(gbase + i_ * 256), \
            (__attribute__((address_space(3))) unsigned int*)(lbase + i_ * 64),       \
            16, 0, 0);                                                        \
} while (0)

#define CONSUME(b_, t_) do {                                                  \
    const f4* row_ = &stage[wid][b_][lane * 25];                              \
    f4 q0_ = row_[0];                                                         \
    float best_ = q0_[0]; int bi_ = 0;                                        \
    if (q0_[1] > best_) { best_ = q0_[1]; bi_ = 1; }                          \
    if (q0_[2] > best_) { best_ = q0_[2]; bi_ = 2; }                          \
    if (q0_[3] > best_) { best_ = q0_[3]; bi_ = 3; }                          \
    _Pragma("unroll")                                                         \
    for (int j_ = 1; j_ < 25; ++j_) {                                         \
        f4 q_ = row_[j_];                                                     \
        if (q_[0] > best_) { best_ = q_[0]; bi_ = 4 * j_; }                   \
        if (q_[1] > best_) { best_ = q_[1]; bi_ = 4 * j_ + 1; }               \
        if (q_[2] > best_) { best_ = q_[2]; bi_ = 4 * j_ + 2; }               \
        if (q_[3] > best_) { best_ = q_[3]; bi_ = 4 * j_ + 3; }               \
    }                                                                         \
    cls[(size_t)(t_) * 64 + lane] = bi_;                                      \
    atomicAdd(&s_cnt[bi_], 1);                                                \
} while (0)

    int t = blockIdx.x * 3 + wid;
    if (t < ntiles) {
        DMA(0, t);
        int cur = 0;
        int tn  = t + S;
        while (tn < ntiles) {
            DMA(cur ^ 1, tn);                         // prefetch next tile
            asm volatile("s_waitcnt vmcnt(25)" ::: "memory");  // cur tile ready
            __builtin_amdgcn_sched_barrier(0);
            CONSUME(cur, t);
            cur ^= 1; t = tn; tn += S;
        }
        asm volatile("s_waitcnt vmcnt(0)" ::: "memory");
        __builtin_amdgcn_sched_barrier(0);
        CONSUME(cur, t);
    }
#undef DMA
#undef CONSUME

    // tail rows (N % 64 != 0) — scalar fallback, block 0 / wave 0 only
    if (blockIdx.x == 0 && wid == 0) {
        const int row = (ntiles << 6) + lane;
        if (row < N) {
            const float* lr = labels + (size_t)row * CC;
            float best = lr[0]; int bi = 0;
            for (int j = 1; j < CC; ++j)
                if (lr[j] > best) { best = lr[j]; bi = j; }
            cls[row] = bi;
            atomicAdd(&s_cnt[bi], 1);
        }
    }

    __syncthreads();
    if (tid < CC) {
        const int c = s_cnt[tid];
        if (c) atomicAdd(&g_counts[tid], c);
    }
}

// ---------------- kernel S0: exclusive scan of counts -> cursors ------------
__global__ void k_scan(const int* __restrict__ g_counts,
                       int* __restrict__ g_cursor)
{
    if (threadIdx.x == 0) {
        int s = 0;
        for (int c = 0; c < CC; ++c) { g_cursor[c] = s; s += g_counts[c]; }
    }
}

// ---------------- kernel S1: scatter rows grouped by class ------------------
__global__ __launch_bounds__(SBT) void k_scatter(
        const int* __restrict__ cls,
        int* __restrict__ g_cursor,
        int* __restrict__ order,
        int* __restrict__ scls,
        int N)
{
    __shared__ int l_hist[CC];
    __shared__ int l_base[CC];
    const int tid = threadIdx.x;
    if (tid < CC) l_hist[tid] = 0;
    __syncthreads();

    const int row = blockIdx.x * SBT + tid;
    const int c = (row < N) ? cls[row] : -1;
    int lr = 0;
    if (c >= 0) lr = atomicAdd(&l_hist[c], 1);       // local rank
    __syncthreads();
    if (tid < CC && l_hist[tid] > 0)
        l_base[tid] = atomicAdd(&g_cursor[tid], l_hist[tid]);
    __syncthreads();
    if (c >= 0) {
        const int pos = l_base[c] + lr;
        order[pos] = row;
        scls[pos]  = c;
    }
}

// ---------------- kernel B: sorted streaming accumulate (2-deep pipeline) ---
// Wave streams 64 consecutive sorted positions; one wave-instruction = one
// full 1KB feature row (always coalesced). Two NAMED register batches fa/fb
// so batch b+1's 8 loads issue while batch b is accumulated (16KB in
// flight/wave). Register accumulator; flush only at class boundaries.
__global__ __launch_bounds__(256) void k_accum_sorted(
        const float* __restrict__ feats,
        const int*   __restrict__ order,
        const int*   __restrict__ scls,
        float* __restrict__ g_sums,
        double* __restrict__ g_sumsq,
        int N)
{
    const int lane = threadIdx.x & 63;
    const int wid  = threadIdx.x >> 6;
    const int idx  = ((blockIdx.x * 4 + wid) << 6) + lane;

    const int ord64 = (idx < N) ? order[idx] : 0;
    const int sc64  = (idx < N) ? scls[idx]  : -1;

    const f4* feats4 = (const f4*)feats;

    f4    acc = {0.f, 0.f, 0.f, 0.f};
    int   cur = -1;
    float ssq = 0.f;
    f4  fa[8], fb[8];
    int ca[8], cb[8];

#define LOADB(F_, C_, B_)                                                     \
    _Pragma("unroll")                                                         \
    for (int r_ = 0; r_ < 8; ++r_) {                                          \
        const int rw_ = __shfl(ord64, (B_) * 8 + r_);                         \
        C_[r_] = __shfl(sc64, (B_) * 8 + r_);                                 \
        F_[r_] = feats4[(size_t)rw_ * (DD / 4) + lane];                       \
    }

#define FLUSH() do {                                                          \
    float* dst_ = g_sums + (size_t)cur * DD + lane * 4;                       \
    unsafeAtomicAdd(dst_ + 0, acc[0]);                                        \
    unsafeAtomicAdd(dst_ + 1, acc[1]);                                        \
    unsafeAtomicAdd(dst_ + 2, acc[2]);                                        \
    unsafeAtomicAdd(dst_ + 3, acc[3]);                                        \
    acc[0] = acc[1] = acc[2] = acc[3] = 0.f;                                  \
} while (0)

#define PROCB(F_, C_)                                                         \
    _Pragma("unroll")                                                         \
    for (int r_ = 0; r_ < 8; ++r_) {                                          \
        if (C_[r_] != cur) {            /* wave-uniform, rare */              \
            if (cur >= 0) FLUSH();                                            \
            cur = C_[r_];                                                     \
        }                                                                     \
        if (cur >= 0) {                                                       \
            acc += F_[r_];                                                    \
            ssq += F_[r_][0] * F_[r_][0] + F_[r_][1] * F_[r_][1]              \
                 + F_[r_][2] * F_[r_][2] + F_[r_][3] * F_[r_][3];             \
        }                                                                     \
    }

    LOADB(fa, ca, 0);
    LOADB(fb, cb, 1);            // 16 KB in flight before first consume
    PROCB(fa, ca);
    LOADB(fa, ca, 2);
    PROCB(fb, cb);
    LOADB(fb, cb, 3);
    PROCB(fa, ca);
    LOADB(fa, ca, 4);
    PROCB(fb, cb);
    LOADB(fb, cb, 5);
    PROCB(fa, ca);
    LOADB(fa, ca, 6);
    PROCB(fb, cb);
    LOADB(fb, cb, 7);
    PROCB(fa, ca);
    PROCB(fb, cb);
    if (cur >= 0) FLUSH();
#undef LOADB
#undef FLUSH
#undef PROCB

    // sumsq: wave reduce -> one f64 atomic per wave
    #pragma unroll
    for (int off = 1; off < 64; off <<= 1) ssq += __shfl_xor(ssq, off);
    if (lane == 0) atomicAdd(g_sumsq, (double)ssq);
}

// ---------------- finalize ---------------------------------------------------
__global__ __launch_bounds__(DD) void affinity_finalize(
        const float* __restrict__ g_sums,
        const int*   __restrict__ g_counts,
        const double* __restrict__ g_sumsq,
        float* __restrict__ out)
{
    const int d = threadIdx.x;

    double colsum = 0.0, s2 = 0.0, dot = 0.0, cc = 0.0;
    for (int c = 0; c < CC; ++c) {
        const int    cnt = g_counts[c];
        const float  s   = g_sums[c * DD + d];
        const double center = (cnt > 0 ? (double)s / (double)cnt : 0.0) + 1e-6;
        colsum += center;
        s2     += center * center;
        dot    += center * (double)s;
        cc     += (double)cnt * center * center;
    }
    double interp = s2 - colsum * colsum / (double)CC;

    __shared__ double red0[DD], red1[DD], red2[DD];
    red0[d] = dot; red1[d] = cc; red2[d] = interp;
    __syncthreads();
    for (int off = DD / 2; off > 0; off >>= 1) {
        if (d < off) {
            red0[d] += red0[d + off];
            red1[d] += red1[d + off];
            red2[d] += red2[d + off];
        }
        __syncthreads();
    }
    if (d == 0) {
        const double intra = *g_sumsq - 2.0 * red0[0] + red1[0];
        const double inter = red2[0] / (double)CC;
        out[0] = (float)(intra / (inter + 1e-6));
    }
}

extern "C" void kernel_launch(void* const* d_in, const int* in_sizes, int n_in,
                              void* d_out, int out_size, void* d_ws, size_t ws_size,
                              hipStream_t stream)
{
    const float* feats  = (const float*)d_in[0];
    const float* labels = (const float*)d_in[1];
    const int N = in_sizes[0] / DD;

    float*  g_sums   = (float*)((char*)d_ws + WS_SUMS_OFF);
    int*    g_counts = (int*)((char*)d_ws + WS_COUNTS_OFF);
    int*    g_cursor = (int*)((char*)d_ws + WS_CURSOR_OFF);
    double* g_sumsq  = (double*)((char*)d_ws + WS_SUMSQ_OFF);
    int*    cls      = (int*)((char*)d_ws + WS_CLS_OFF);
    int*    order    = cls + N;
    int*    scls     = order + N;

    hipMemsetAsync(d_ws, 0, WS_HDR, stream);     // zero sums/counts/cursor/sumsq

    k_argmax<<<256, 192, 0, stream>>>(labels, cls, g_counts, N);

    k_scan<<<1, 64, 0, stream>>>(g_counts, g_cursor);

    const int nbS = (N + SBT - 1) / SBT;
    k_scatter<<<nbS, SBT, 0, stream>>>(cls, g_cursor, order, scls, N);

    const int nbB = (N + 255) / 256;             // 4 waves x 64 rows per block
    k_accum_sorted<<<nbB, 256, 0, stream>>>(feats, order, scls, g_sums,
                                            g_sumsq, N);

    affinity_finalize<<<1, DD, 0, stream>>>(g_sums, g_counts, g_sumsq,
                                            (float*)d_out);
}

// Round 11
// 138.031 us; speedup vs baseline: 5.5010x; 1.1483x over previous
//
#include <hip/hip_runtime.h>

#define DD   256    // feature dim
#define CC   100    // num classes
#define SBT  1024   // scatter threads per block

typedef float f4 __attribute__((ext_vector_type(4)));

// Workspace layout (bytes):
//   [0, 102400)        : g_sums   (CC*DD f32, natural layout)
//   [102400, 102800)   : g_counts (CC int)
//   [102800, 103200)   : g_cursor (CC int)
//   [103200, 103208)   : g_sumsq  (1 double)
//   [103424, +4N)      : cls      (N int)
//   [+4N, +8N)         : order    (N int)
//   [+8N, +12N)        : scls     (N int)
#define WS_SUMS_OFF   0
#define WS_COUNTS_OFF (CC * DD * 4)
#define WS_CURSOR_OFF (WS_COUNTS_OFF + CC * 4)
#define WS_SUMSQ_OFF  (WS_CURSOR_OFF + CC * 4)
#define WS_HDR        (WS_SUMSQ_OFF + 8)
#define WS_CLS_OFF    103424

// ---------------- kernel A: argmax via DMA-staged LDS tiles -----------------
// (unchanged from round 10 — est. >=5 TB/s) Each wave: 2x25.6KB LDS ping-pong,
// 25 global_load_lds width-16 per tile, counted vmcnt(25), per-lane row argmax.
__global__ __launch_bounds__(192) void k_argmax(
        const float* __restrict__ labels,
        int*   __restrict__ cls,
        int*   __restrict__ g_counts,
        int N)
{
    __shared__ f4  stage[3][2][1600];    // 3 waves x 2 bufs x 25600 B = 150 KB
    __shared__ int s_cnt[CC];

    const int tid  = threadIdx.x;
    const int lane = tid & 63;
    const int wid  = tid >> 6;
    if (tid < CC) s_cnt[tid] = 0;
    __syncthreads();

    const int ntiles = N >> 6;
    const int S      = gridDim.x * 3;    // total waves

#define DMA(b_, t_) do {                                                      \
    const float* gbase = labels + (size_t)(t_) * 6400 + lane * 4;             \
    f4* lbase = &stage[wid][b_][0];                                           \
    _Pragma("unroll")                                                         \
    for (int i_ = 0; i_ < 25; ++i_)                                           \
        __builtin_amdgcn_global_load_lds(                                     \
            (const __attribute__((address_space(1))) unsigned int*)(gbase + i_ * 256), \
            (__attribute__((address_space(3))) unsigned int*)(lbase + i_ * 64),       \
            16, 0, 0);                                                        \
} while (0)

#define CONSUME(b_, t_) do {                                                  \
    const f4* row_ = &stage[wid][b_][lane * 25];                              \
    f4 q0_ = row_[0];                                                         \
    float best_ = q0_[0]; int bi_ = 0;                                        \
    if (q0_[1] > best_) { best_ = q0_[1]; bi_ = 1; }                          \
    if (q0_[2] > best_) { best_ = q0_[2]; bi_ = 2; }                          \
    if (q0_[3] > best_) { best_ = q0_[3]; bi_ = 3; }                          \
    _Pragma("unroll")                                                         \
    for (int j_ = 1; j_ < 25; ++j_) {                                         \
        f4 q_ = row_[j_];                                                     \
        if (q_[0] > best_) { best_ = q_[0]; bi_ = 4 * j_; }                   \
        if (q_[1] > best_) { best_ = q_[1]; bi_ = 4 * j_ + 1; }               \
        if (q_[2] > best_) { best_ = q_[2]; bi_ = 4 * j_ + 2; }               \
        if (q_[3] > best_) { best_ = q_[3]; bi_ = 4 * j_ + 3; }               \
    }                                                                         \
    cls[(size_t)(t_) * 64 + lane] = bi_;                                      \
    atomicAdd(&s_cnt[bi_], 1);                                                \
} while (0)

    int t = blockIdx.x * 3 + wid;
    if (t < ntiles) {
        DMA(0, t);
        int cur = 0;
        int tn  = t + S;
        while (tn < ntiles) {
            DMA(cur ^ 1, tn);                         // prefetch next tile
            asm volatile("s_waitcnt vmcnt(25)" ::: "memory");  // cur tile ready
            __builtin_amdgcn_sched_barrier(0);
            CONSUME(cur, t);
            cur ^= 1; t = tn; tn += S;
        }
        asm volatile("s_waitcnt vmcnt(0)" ::: "memory");
        __builtin_amdgcn_sched_barrier(0);
        CONSUME(cur, t);
    }
#undef DMA
#undef CONSUME

    // tail rows (N % 64 != 0)
    if (blockIdx.x == 0 && wid == 0) {
        const int row = (ntiles << 6) + lane;
        if (row < N) {
            const float* lr = labels + (size_t)row * CC;
            float best = lr[0]; int bi = 0;
            for (int j = 1; j < CC; ++j)
                if (lr[j] > best) { best = lr[j]; bi = j; }
            cls[row] = bi;
            atomicAdd(&s_cnt[bi], 1);
        }
    }

    __syncthreads();
    if (tid < CC) {
        const int c = s_cnt[tid];
        if (c) atomicAdd(&g_counts[tid], c);
    }
}

// ---------------- kernel S: scatter with in-block scan (k_scan folded in) ---
__global__ __launch_bounds__(SBT) void k_scatter(
        const int* __restrict__ cls,
        const int* __restrict__ g_counts,
        int* __restrict__ g_cursor,
        int* __restrict__ order,
        int* __restrict__ scls,
        int N)
{
    __shared__ int l_hist[CC];
    __shared__ int l_base[CC];
    __shared__ int l_scan[CC];
    const int tid = threadIdx.x;
    if (tid < CC) { l_hist[tid] = 0; l_scan[tid] = g_counts[tid]; }
    __syncthreads();

    if (tid == 0) {                      // exclusive prefix over LDS (fast)
        int run = 0;
        for (int c = 0; c < CC; ++c) { const int t = l_scan[c]; l_scan[c] = run; run += t; }
    }
    const int row = blockIdx.x * SBT + tid;
    const int c = (row < N) ? cls[row] : -1;
    int lr = 0;
    if (c >= 0) lr = atomicAdd(&l_hist[c], 1);       // local rank
    __syncthreads();                     // scan + hist both done

    if (tid < CC && l_hist[tid] > 0)
        l_base[tid] = l_scan[tid] + atomicAdd(&g_cursor[tid], l_hist[tid]);
    __syncthreads();

    if (c >= 0) {
        const int pos = l_base[c] + lr;
        order[pos] = row;
        scls[pos]  = c;
    }
}

// ---------------- kernel B: sorted streaming accumulate ---------------------
// Wave streams 64 sorted positions. order/scls staged in LDS once; per row:
// broadcast ds_read + readfirstlane -> SGPR row index -> saddr-form vector
// load of the full 1KB feature row. No ds_bpermute chains. 4-deep named
// pipeline (fA..fD x 4 rows) keeps ~12KB/wave in flight. Class logic is
// fully scalar (uniform branches); accumulator in VGPRs; flush only at
// class boundaries via fire-and-forget global f32 atomics.
__global__ __launch_bounds__(256) void k_accum_sorted(
        const float* __restrict__ feats,
        const int*   __restrict__ order,
        const int*   __restrict__ scls,
        float* __restrict__ g_sums,
        double* __restrict__ g_sumsq,
        int N)
{
    __shared__ int s_ord[256];
    __shared__ int s_scl[256];

    const int tid  = threadIdx.x;
    const int lane = tid & 63;
    const int wid  = tid >> 6;
    const int gidx = blockIdx.x * 256 + tid;

    s_ord[tid] = (gidx < N) ? order[gidx] : 0;
    s_scl[tid] = (gidx < N) ? scls[gidx]  : -1;
    __syncthreads();

    const int wb = wid * 64;             // wave's window into s_ord/s_scl
    const f4* feats4 = (const f4*)feats;

    f4    acc = {0.f, 0.f, 0.f, 0.f};
    int   cur = -1;
    float ssq = 0.f;

    f4  fA[4], fB[4], fC[4], fD[4];
    int cA[4], cB[4], cC[4], cD[4];

#define LOADB(F_, C_, B_)                                                     \
    _Pragma("unroll")                                                         \
    for (int r_ = 0; r_ < 4; ++r_) {                                          \
        const int k_  = wb + (B_) * 4 + r_;                                   \
        const int rw_ = __builtin_amdgcn_readfirstlane(s_ord[k_]);            \
        C_[r_] = __builtin_amdgcn_readfirstlane(s_scl[k_]);                   \
        F_[r_] = feats4[((size_t)rw_ << 6) + lane];                           \
    }

#define FLUSH() do {                                                          \
    float* dst_ = g_sums + (size_t)cur * DD + lane * 4;                       \
    unsafeAtomicAdd(dst_ + 0, acc[0]);                                        \
    unsafeAtomicAdd(dst_ + 1, acc[1]);                                        \
    unsafeAtomicAdd(dst_ + 2, acc[2]);                                        \
    unsafeAtomicAdd(dst_ + 3, acc[3]);                                        \
    acc[0] = acc[1] = acc[2] = acc[3] = 0.f;                                  \
} while (0)

#define PROCB(F_, C_)                                                         \
    _Pragma("unroll")                                                         \
    for (int r_ = 0; r_ < 4; ++r_) {                                          \
        if (C_[r_] != cur) {            /* scalar compare, uniform branch */  \
            if (cur >= 0) FLUSH();                                            \
            cur = C_[r_];                                                     \
        }                                                                     \
        if (cur >= 0) {                                                       \
            acc += F_[r_];                                                    \
            ssq += F_[r_][0] * F_[r_][0] + F_[r_][1] * F_[r_][1]              \
                 + F_[r_][2] * F_[r_][2] + F_[r_][3] * F_[r_][3];             \
        }                                                                     \
    }

    LOADB(fA, cA, 0); LOADB(fB, cB, 1); LOADB(fC, cC, 2); LOADB(fD, cD, 3);
    PROCB(fA, cA); LOADB(fA, cA, 4);
    PROCB(fB, cB); LOADB(fB, cB, 5);
    PROCB(fC, cC); LOADB(fC, cC, 6);
    PROCB(fD, cD); LOADB(fD, cD, 7);
    PROCB(fA, cA); LOADB(fA, cA, 8);
    PROCB(fB, cB); LOADB(fB, cB, 9);
    PROCB(fC, cC); LOADB(fC, cC, 10);
    PROCB(fD, cD); LOADB(fD, cD, 11);
    PROCB(fA, cA); LOADB(fA, cA, 12);
    PROCB(fB, cB); LOADB(fB, cB, 13);
    PROCB(fC, cC); LOADB(fC, cC, 14);
    PROCB(fD, cD); LOADB(fD, cD, 15);
    PROCB(fA, cA); PROCB(fB, cB); PROCB(fC, cC); PROCB(fD, cD);
    if (cur >= 0) FLUSH();
#undef LOADB
#undef FLUSH
#undef PROCB

    // sumsq: wave reduce -> one f64 atomic per wave
    #pragma unroll
    for (int off = 1; off < 64; off <<= 1) ssq += __shfl_xor(ssq, off);
    if (lane == 0) atomicAdd(g_sumsq, (double)ssq);
}

// ---------------- finalize (batched independent loads) ----------------------
__global__ __launch_bounds__(DD) void affinity_finalize(
        const float* __restrict__ g_sums,
        const int*   __restrict__ g_counts,
        const double* __restrict__ g_sumsq,
        float* __restrict__ out)
{
    const int d = threadIdx.x;
    __shared__ int s_cnt[CC];
    if (d < CC) s_cnt[d] = g_counts[d];
    __syncthreads();

    double colsum = 0.0, s2 = 0.0, dot = 0.0, cc = 0.0;
    for (int cb = 0; cb < CC; cb += 4) {         // CC % 4 == 0
        float s[4];
        #pragma unroll
        for (int k = 0; k < 4; ++k)              // 4 independent loads in flight
            s[k] = g_sums[(size_t)(cb + k) * DD + d];
        #pragma unroll
        for (int k = 0; k < 4; ++k) {
            const int    cnt = s_cnt[cb + k];
            const double center = (cnt > 0 ? (double)s[k] / (double)cnt : 0.0) + 1e-6;
            colsum += center;
            s2     += center * center;
            dot    += center * (double)s[k];
            cc     += (double)cnt * center * center;
        }
    }
    double interp = s2 - colsum * colsum / (double)CC;

    __shared__ double red0[DD], red1[DD], red2[DD];
    red0[d] = dot; red1[d] = cc; red2[d] = interp;
    __syncthreads();
    for (int off = DD / 2; off > 0; off >>= 1) {
        if (d < off) {
            red0[d] += red0[d + off];
            red1[d] += red1[d + off];
            red2[d] += red2[d + off];
        }
        __syncthreads();
    }
    if (d == 0) {
        const double intra = *g_sumsq - 2.0 * red0[0] + red1[0];
        const double inter = red2[0] / (double)CC;
        out[0] = (float)(intra / (inter + 1e-6));
    }
}

extern "C" void kernel_launch(void* const* d_in, const int* in_sizes, int n_in,
                              void* d_out, int out_size, void* d_ws, size_t ws_size,
                              hipStream_t stream)
{
    const float* feats  = (const float*)d_in[0];
    const float* labels = (const float*)d_in[1];
    const int N = in_sizes[0] / DD;

    float*  g_sums   = (float*)((char*)d_ws + WS_SUMS_OFF);
    int*    g_counts = (int*)((char*)d_ws + WS_COUNTS_OFF);
    int*    g_cursor = (int*)((char*)d_ws + WS_CURSOR_OFF);
    double* g_sumsq  = (double*)((char*)d_ws + WS_SUMSQ_OFF);
    int*    cls      = (int*)((char*)d_ws + WS_CLS_OFF);
    int*    order    = cls + N;
    int*    scls     = order + N;

    hipMemsetAsync(d_ws, 0, WS_HDR, stream);     // zero sums/counts/cursor/sumsq

    k_argmax<<<256, 192, 0, stream>>>(labels, cls, g_counts, N);

    const int nbS = (N + SBT - 1) / SBT;
    k_scatter<<<nbS, SBT, 0, stream>>>(cls, g_counts, g_cursor, order, scls, N);

    const int nbB = (N + 255) / 256;             // 4 waves x 64 rows per block
    k_accum_sorted<<<nbB, 256, 0, stream>>>(feats, order, scls, g_sums,
                                            g_sumsq, N);

    affinity_finalize<<<1, DD, 0, stream>>>(g_sums, g_counts, g_sumsq,
                                            (float*)d_out);
}